// Round 8
// baseline (567.421 us; speedup 1.0000x reference)
//
#include <hip/hip_runtime.h>

#define NN 50000
#define NE 600000
#define NG 512
#define HD 128
#define EPSV 1e-5f

typedef unsigned int uint;

__device__ inline void atomicAddF(float* p, float v) {
  __hip_atomic_fetch_add(p, v, __ATOMIC_RELAXED, __HIP_MEMORY_SCOPE_AGENT);
}

__device__ inline uint bf16rne(float f) {
  uint u = __float_as_uint(f);
  return (u + 0x7fffu + ((u >> 16) & 1u)) >> 16;
}
__device__ inline uint pack2bf(float a, float b) {
  return bf16rne(a) | (bf16rne(b) << 16);
}
__device__ inline float lo16f(uint u) { return __uint_as_float(u << 16); }
__device__ inline float hi16f(uint u) { return __uint_as_float(u & 0xffff0000u); }

// ---- CSR build (self-edge first in each node's list) ----
__global__ __launch_bounds__(256) void k_count(const int* __restrict__ dst, int* __restrict__ cnt) {
  int e = blockIdx.x * 256 + threadIdx.x;
  if (e < NE) atomicAdd(&cnt[dst[e]], 1);
}

// 4 elements per thread, 13 iterations; also zeroes Abf's pad row NN.
__global__ __launch_bounds__(1024) void k_scan(const int* __restrict__ cnt, int* __restrict__ off,
                                               int* __restrict__ cursor, float* __restrict__ dinv,
                                               int* __restrict__ csr, uint* __restrict__ zrow) {
  __shared__ int part[16];
  __shared__ int partscan[16];
  int t = threadIdx.x;
  int lane = t & 63, w = t >> 6;
  if (t < 64) zrow[t] = 0u;   // zero pad row (bf16 row = 64 uints)
  int carry = 0;
  for (int base = 0; base < NN; base += 4096) {
    int i0 = base + 4 * t;
    int c[4], v[4];
#pragma unroll
    for (int j = 0; j < 4; j++) {
      int idx = i0 + j;
      c[j] = (idx < NN) ? cnt[idx] : 0;
      v[j] = (idx < NN) ? (c[j] + 1) : 0;
    }
    int tsum = (v[0] + v[1]) + (v[2] + v[3]);
    int val = tsum;
#pragma unroll
    for (int s = 1; s < 64; s <<= 1) {
      int u = __shfl_up(val, s);
      if (lane >= s) val += u;
    }
    if (lane == 63) part[w] = val;
    __syncthreads();
    if (t == 0) {
      int acc = 0;
#pragma unroll
      for (int i = 0; i < 16; i++) { acc += part[i]; partscan[i] = acc; }
    }
    __syncthreads();
    int waveoff = (w > 0) ? partscan[w - 1] : 0;
    int run = val - tsum + waveoff + carry;
#pragma unroll
    for (int j = 0; j < 4; j++) {
      int idx = i0 + j;
      if (idx < NN) {
        off[idx] = run;
        cursor[idx] = run + 1;
        csr[run] = idx;                        // self-edge
        dinv[idx] = rsqrtf((float)c[j] + 1.0f);
        run += v[j];
      }
    }
    carry += partscan[15];
    __syncthreads();
  }
  if (t == 0) off[NN] = carry;
}

__global__ __launch_bounds__(256) void k_fill(const int* __restrict__ src, const int* __restrict__ dst,
                                              int* __restrict__ cursor, int* __restrict__ csr) {
  int e = blockIdx.x * 256 + threadIdx.x;
  if (e < NE) {
    int p = atomicAdd(&cursor[dst[e]], 1);
    csr[p] = src[e];
  }
}

// ---- fused embedding tables: T = emb @ W1[rows] ----
__global__ __launch_bounds__(128) void k_tabs(const float* __restrict__ emb0, const float* __restrict__ emb1,
                                              const float* __restrict__ emb2, const float* __restrict__ emb5,
                                              const float* __restrict__ W1, float* __restrict__ tabs,
                                              float* __restrict__ row0) {
  int r = blockIdx.x, f = threadIdx.x;
  if (r == 470) { row0[f] = W1[f]; return; }
  const float* e;
  int wbase;
  if (r < 96)      { e = emb0 + r * 32;        wbase = 1;  }
  else if (r < 192){ e = emb1 + (r - 96) * 32; wbase = 33; }
  else if (r < 288){ e = emb2 + (r - 192) * 32; wbase = 65; }
  else             { e = emb5 + (r - 288) * 32; wbase = 97; }
  float acc = 0.f;
#pragma unroll 8
  for (int k = 0; k < 32; k++) acc += e[k] * W1[(wbase + k) * HD + f];
  tabs[r * HD + f] = acc;
}

// ---- layer-1: embed + axpy + pre-scale by dinv; packed bf16 output ----
__global__ __launch_bounds__(256) void k_embed(const float* __restrict__ x, const float2* __restrict__ tabs2,
                                               const float2* __restrict__ row02, const float* __restrict__ dinv,
                                               uint* __restrict__ Abf) {
  int n = blockIdx.x * 4 + (threadIdx.x >> 6);   // grid exact: 12500*4 = NN
  int lane = threadIdx.x & 63;
  float poss = x[n * 5 + 0];
  int i0 = (int)x[n * 5 + 1];
  int i1 = (int)x[n * 5 + 2];
  int i2 = (int)x[n * 5 + 3];
  int i5 = (int)x[n * 5 + 4];
  float2 r0 = row02[lane];
  float2 t0 = tabs2[(size_t)i0 * 64 + lane];
  float2 t1 = tabs2[(size_t)(96 + i1) * 64 + lane];
  float2 t2 = tabs2[(size_t)(192 + i2) * 64 + lane];
  float2 t5 = tabs2[(size_t)(288 + i5) * 64 + lane];
  float hx = poss * r0.x + t0.x + t1.x + t2.x + t5.x;
  float hy = poss * r0.y + t0.y + t1.y + t2.y + t5.y;
  float dv = dinv[n];
  Abf[(size_t)n * 64 + lane] = pack2bf(hx * dv, hy * dv);
}

// ---- aggregation v8: all 4 nodes' first-batch gathers issued upfront
// (16 uint4 loads in flight per wave), then per-node consume.
// Row = 256B bf16 = 16 lanes x uint4; lane-group grp takes neighbor 4j+grp;
// cross-group combine by shfl_xor butterfly. CSR = [self, neighbors...].
// B[n] = dinv[n]*sum(Abf rows) + bias. Pads read zeroed row NN.
#define AGG_NPW 4
#define AGG_NPB (4 * AGG_NPW)
__global__ __launch_bounds__(256) void k_agg(const uint* __restrict__ Abf, const int* __restrict__ off,
                                             const int* __restrict__ csr, const float* __restrict__ dinv,
                                             const float* __restrict__ bias, float* __restrict__ B,
                                             float* __restrict__ stats) {
  const int t = threadIdx.x, lane = t & 63, wave = t >> 6;
  const int grp = lane >> 4, p = lane & 15;
  __shared__ float sredb[16][17];   // [p][8 sums + 8 sumsqs], padded
  for (int q = t; q < 16 * 17; q += 256) ((float*)sredb)[q] = 0.f;
  __syncthreads();

  const float4 bias03 = ((const float4*)bias)[p * 2];
  const float4 bias47 = ((const float4*)bias)[p * 2 + 1];

  const int n0 = blockIdx.x * AGG_NPB + wave * AGG_NPW;   // grid exact
  int sv = 0;
  { int q = n0 + lane; if (lane <= AGG_NPW) sv = off[q]; }

  // preload all 4 nodes' first-64 edge indices
  int ev[AGG_NPW];
#pragma unroll
  for (int i = 0; i < AGG_NPW; i++) {
    int ks = __shfl(sv, i), ke = __shfl(sv, i + 1);
    int rem = ke - ks;
    ev[i] = (lane < rem) ? csr[ks + lane] : NN;
  }

  // ---- Phase 1: issue ALL first-batch gathers (16 loads, no waits between)
  uint4 v[AGG_NPW][4];
#pragma unroll
  for (int i = 0; i < AGG_NPW; i++) {
#pragma unroll
    for (int m = 0; m < 4; m++) {
      int nb = __shfl(ev[i], 4 * m + grp);   // pad slots give NN
      v[i][m] = *(const uint4*)((const char*)Abf + (((size_t)nb) << 8) + (p << 4));
    }
  }

  // ---- Phase 2: per-node consume + rare deg>16 tail + butterfly + store
#pragma unroll 1
  for (int i = 0; i < AGG_NPW; i++) {
    const int ks = __shfl(sv, i);
    const int ke = __shfl(sv, i + 1);
    const int deg = ke - ks;
    float acc[8] = {0.f, 0.f, 0.f, 0.f, 0.f, 0.f, 0.f, 0.f};
#pragma unroll
    for (int m = 0; m < 4; m++) {
      acc[0] += lo16f(v[i][m].x); acc[1] += hi16f(v[i][m].x);
      acc[2] += lo16f(v[i][m].y); acc[3] += hi16f(v[i][m].y);
      acc[4] += lo16f(v[i][m].z); acc[5] += hi16f(v[i][m].z);
      acc[6] += lo16f(v[i][m].w); acc[7] += hi16f(v[i][m].w);
    }
    // tail: edges 16..deg (15% of nodes; >64 ultra-rare)
#pragma unroll 1
    for (int c0 = 16; c0 < deg; c0 += 16) {
      uint4 w[4];
      if (c0 + 16 <= 64) {
#pragma unroll
        for (int m = 0; m < 4; m++) {
          int nb = __shfl(ev[i], c0 + 4 * m + grp);
          w[m] = *(const uint4*)((const char*)Abf + (((size_t)nb) << 8) + (p << 4));
        }
      } else {
        int rem2 = deg - c0;
        int evr = (lane < rem2) ? csr[ks + c0 + lane] : NN;
#pragma unroll
        for (int m = 0; m < 4; m++) {
          int nb = __shfl(evr, 4 * m + grp);
          w[m] = *(const uint4*)((const char*)Abf + (((size_t)nb) << 8) + (p << 4));
        }
      }
#pragma unroll
      for (int m = 0; m < 4; m++) {
        acc[0] += lo16f(w[m].x); acc[1] += hi16f(w[m].x);
        acc[2] += lo16f(w[m].y); acc[3] += hi16f(w[m].y);
        acc[4] += lo16f(w[m].z); acc[5] += hi16f(w[m].z);
        acc[6] += lo16f(w[m].w); acc[7] += hi16f(w[m].w);
      }
    }
    // combine the 4 lane-groups (disjoint neighbor subsets)
#pragma unroll
    for (int q = 0; q < 8; q++) {
      acc[q] += __shfl_xor(acc[q], 16);
      acc[q] += __shfl_xor(acc[q], 32);
    }
    const float dv = dinv[n0 + i];
    float o[8];
    o[0] = fmaf(acc[0], dv, bias03.x); o[1] = fmaf(acc[1], dv, bias03.y);
    o[2] = fmaf(acc[2], dv, bias03.z); o[3] = fmaf(acc[3], dv, bias03.w);
    o[4] = fmaf(acc[4], dv, bias47.x); o[5] = fmaf(acc[5], dv, bias47.y);
    o[6] = fmaf(acc[6], dv, bias47.z); o[7] = fmaf(acc[7], dv, bias47.w);
    if (grp == 0) {
      float4 w0 = make_float4(o[0], o[1], o[2], o[3]);
      float4 w1 = make_float4(o[4], o[5], o[6], o[7]);
      *(float4*)&B[(size_t)(n0 + i) * HD + p * 8] = w0;
      *(float4*)&B[(size_t)(n0 + i) * HD + p * 8 + 4] = w1;
#pragma unroll
      for (int q = 0; q < 8; q++) {
        atomicAdd(&sredb[p][q], o[q]);
        atomicAdd(&sredb[p][8 + q], o[q] * o[q]);
      }
    }
  }
  __syncthreads();
  {
    int pp = t >> 4, ii = t & 15;
    float v2 = sredb[pp][ii];
    atomicAddF(&stats[(ii < 8 ? 0 : 128) + pp * 8 + (ii & 7)], v2);
  }
}

// ---- BN finalize -> affine a,c ----
__global__ __launch_bounds__(128) void k_affine(const float* __restrict__ stats, const float* __restrict__ g,
                                                const float* __restrict__ be, float* __restrict__ af,
                                                float* __restrict__ cf) {
  int f = threadIdx.x;
  float mean = stats[f] * (1.f / NN);
  float var = stats[128 + f] * (1.f / NN) - mean * mean;
  var = fmaxf(var, 0.f);
  float inv = rsqrtf(var + EPSV);
  float a = g[f] * inv;
  af[f] = a;
  cf[f] = be[f] - mean * a;
}

// ---- GEMM: Abf[n,:] = bf16( dinv[n] * (relu(af*Bin[n,:]+cf) @ W) ) ----
#define GT_N 128
#define GT_KC 32
__global__ __launch_bounds__(256) void k_gemm(const float* __restrict__ Bin, const float* __restrict__ W,
                                              const float* __restrict__ af, const float* __restrict__ cf,
                                              const float* __restrict__ dinv, uint* __restrict__ Abf) {
  __shared__ float hs[GT_KC * 132];
  __shared__ float ws[GT_KC * 132];
  const int t = threadIdx.x;
  const int base = blockIdx.x * GT_N;
  const int tx = t & 15, ty = t >> 4;
  float acc[8][8];
#pragma unroll
  for (int a = 0; a < 8; a++)
#pragma unroll
    for (int b = 0; b < 8; b++) acc[a][b] = 0.f;

  for (int k0 = 0; k0 < HD; k0 += GT_KC) {
    __syncthreads();
    {
      const float4* W4 = (const float4*)(W + k0 * HD);
#pragma unroll
      for (int i = t; i < 1024; i += 256) {
        int row = i >> 5, c4 = i & 31;
        float4 v = W4[i];
        *(float4*)&ws[row * 132 + c4 * 4] = v;
      }
    }
    {
#pragma unroll
      for (int i = t; i < 1024; i += 256) {
        int node = i >> 3, c4 = i & 7;
        int n = base + node;
        float4 v = make_float4(0.f, 0.f, 0.f, 0.f);
        if (n < NN) v = *(const float4*)&Bin[(size_t)n * HD + k0 + c4 * 4];
        int kk = c4 * 4;
        float r0 = fmaxf(fmaf(af[k0 + kk + 0], v.x, cf[k0 + kk + 0]), 0.f);
        float r1 = fmaxf(fmaf(af[k0 + kk + 1], v.y, cf[k0 + kk + 1]), 0.f);
        float r2 = fmaxf(fmaf(af[k0 + kk + 2], v.z, cf[k0 + kk + 2]), 0.f);
        float r3 = fmaxf(fmaf(af[k0 + kk + 3], v.w, cf[k0 + kk + 3]), 0.f);
        hs[(kk + 0) * 132 + node] = r0;
        hs[(kk + 1) * 132 + node] = r1;
        hs[(kk + 2) * 132 + node] = r2;
        hs[(kk + 3) * 132 + node] = r3;
      }
    }
    __syncthreads();
#pragma unroll
    for (int k = 0; k < GT_KC; k++) {
      float4 h0 = *(float4*)&hs[k * 132 + ty * 8];
      float4 h1 = *(float4*)&hs[k * 132 + ty * 8 + 4];
      float4 w0 = *(float4*)&ws[k * 132 + tx * 8];
      float4 w1 = *(float4*)&ws[k * 132 + tx * 8 + 4];
      float hh[8] = {h0.x, h0.y, h0.z, h0.w, h1.x, h1.y, h1.z, h1.w};
      float wv[8] = {w0.x, w0.y, w0.z, w0.w, w1.x, w1.y, w1.z, w1.w};
#pragma unroll
      for (int a = 0; a < 8; a++)
#pragma unroll
        for (int b = 0; b < 8; b++) acc[a][b] = fmaf(hh[a], wv[b], acc[a][b]);
    }
  }
#pragma unroll
  for (int a = 0; a < 8; a++) {
    int n = base + ty * 8 + a;
    if (n < NN) {
      float s = dinv[n];
      uint4 o;
      o.x = pack2bf(acc[a][0] * s, acc[a][1] * s);
      o.y = pack2bf(acc[a][2] * s, acc[a][3] * s);
      o.z = pack2bf(acc[a][4] * s, acc[a][5] * s);
      o.w = pack2bf(acc[a][6] * s, acc[a][7] * s);
      *(uint4*)&Abf[(size_t)n * 64 + tx * 4] = o;
    }
  }
}

// ---- graph boundaries via binary search on sorted batch ----
__global__ __launch_bounds__(128) void k_bsearch(const int* __restrict__ batch, int* __restrict__ gstart) {
  int g = blockIdx.x * 128 + threadIdx.x;
  if (g > NG) return;
  if (g == NG) { gstart[NG] = NN; return; }
  int lo = 0, hi = NN;
  while (lo < hi) {
    int mid = (lo + hi) >> 1;
    if (batch[mid] < g) lo = mid + 1;
    else hi = mid;
  }
  gstart[g] = lo;
}

// ---- pool + FC ----
__global__ __launch_bounds__(128) void k_pool(const float* __restrict__ B, const float* __restrict__ af,
                                              const float* __restrict__ cf, const int* __restrict__ gstart,
                                              const float* __restrict__ fcW, const float* __restrict__ fcb,
                                              float* __restrict__ out) {
  int g = blockIdx.x, f = threadIdx.x;
  int gs = gstart[g], ge = gstart[g + 1];
  float a = af[f], c = cf[f];
  float a0 = 0.f, a1 = 0.f, a2 = 0.f, a3 = 0.f;
  int n = gs;
  for (; n + 4 <= ge; n += 4) {
    a0 += fmaxf(fmaf(a, B[(size_t)(n + 0) * HD + f], c), 0.f);
    a1 += fmaxf(fmaf(a, B[(size_t)(n + 1) * HD + f], c), 0.f);
    a2 += fmaxf(fmaf(a, B[(size_t)(n + 2) * HD + f], c), 0.f);
    a3 += fmaxf(fmaf(a, B[(size_t)(n + 3) * HD + f], c), 0.f);
  }
  for (; n < ge; n++) a0 += fmaxf(fmaf(a, B[(size_t)n * HD + f], c), 0.f);
  float acc = (a0 + a1) + (a2 + a3);
  float cntf = (float)(ge - gs);
  float pooled = acc / fmaxf(cntf, 1.f);
  __shared__ float lp[128];
  lp[f] = pooled;
  __syncthreads();
  if (f < 3) {
    float o = fcb[f];
    for (int k = 0; k < 128; k++) o += lp[k] * fcW[k * 3 + f];
    out[g * 3 + f] = o;
  }
}

extern "C" void kernel_launch(void* const* d_in, const int* in_sizes, int n_in,
                              void* d_out, int out_size, void* d_ws, size_t ws_size,
                              hipStream_t stream) {
  const float* x    = (const float*)d_in[0];
  const int* ei     = (const int*)d_in[1];
  const int* batch  = (const int*)d_in[2];
  const float* emb0 = (const float*)d_in[3];
  const float* emb1 = (const float*)d_in[4];
  const float* emb2 = (const float*)d_in[5];
  const float* emb5 = (const float*)d_in[6];
  const float* W1   = (const float*)d_in[7];
  const float* b1   = (const float*)d_in[8];
  const float* W2   = (const float*)d_in[9];
  const float* b2   = (const float*)d_in[10];
  const float* W3   = (const float*)d_in[11];
  const float* b3   = (const float*)d_in[12];
  const float* g1   = (const float*)d_in[13];
  const float* be1  = (const float*)d_in[14];
  const float* g2   = (const float*)d_in[15];
  const float* be2  = (const float*)d_in[16];
  const float* g3   = (const float*)d_in[17];
  const float* be3  = (const float*)d_in[18];
  const float* fcW  = (const float*)d_in[19];
  const float* fcb  = (const float*)d_in[20];
  float* out = (float*)d_out;

  const int* esrc = ei;
  const int* edst = ei + NE;

  char* p = (char*)d_ws;
  size_t o = 0;
  auto alloc = [&](size_t bytes) -> void* {
    o = (o + 255) & ~(size_t)255;
    void* r = p + o;
    o += bytes;
    return r;
  };
  int* cnt      = (int*)alloc(NN * 4);
  float* stats  = (float*)alloc(3 * 256 * 4);   // 3 layers x (sum,sumsq)
  size_t zbytes = o;                            // memset range covers cnt+stats
  int* off      = (int*)alloc((NN + 1) * 4);
  int* cursor   = (int*)alloc(NN * 4);
  int* csr      = (int*)alloc((size_t)(NE + NN + 64) * 4);
  float* dinv   = (float*)alloc(NN * 4);
  float* tabs   = (float*)alloc(470 * HD * 4);
  float* row0   = (float*)alloc(HD * 4);
  float* affine = (float*)alloc(3 * 256 * 4);   // 3 layers x (a,c)
  int* gstart   = (int*)alloc((NG + 1) * 4);
  uint* Abf     = (uint*)alloc((size_t)(NN + 1) * 64 * 4);   // bf16 rows, 256B each (+pad row)
  float* bufB   = (float*)alloc((size_t)NN * HD * 4);
  (void)ws_size; (void)n_in; (void)in_sizes; (void)out_size;

  hipMemsetAsync(d_ws, 0, zbytes, stream);

  k_count<<<(NE + 255) / 256, 256, 0, stream>>>(edst, cnt);
  k_scan<<<1, 1024, 0, stream>>>(cnt, off, cursor, dinv, csr, Abf + (size_t)NN * 64);
  k_fill<<<(NE + 255) / 256, 256, 0, stream>>>(esrc, edst, cursor, csr);
  k_tabs<<<471, 128, 0, stream>>>(emb0, emb1, emb2, emb5, W1, tabs, row0);
  k_bsearch<<<5, 128, 0, stream>>>(batch, gstart);
  k_embed<<<NN / 4, 256, 0, stream>>>(x, (const float2*)tabs, (const float2*)row0, dinv, Abf);

  const int nagg = NN / AGG_NPB;            // 3125, exact
  const int ngemm = (NN + GT_N - 1) / GT_N;

  // layer 1
  k_agg<<<nagg, 256, 0, stream>>>(Abf, off, csr, dinv, b1, bufB, stats + 0);
  k_affine<<<1, 128, 0, stream>>>(stats + 0, g1, be1, affine + 0, affine + 128);
  // layer 2
  k_gemm<<<ngemm, 256, 0, stream>>>(bufB, W2, affine + 0, affine + 128, dinv, Abf);
  k_agg<<<nagg, 256, 0, stream>>>(Abf, off, csr, dinv, b2, bufB, stats + 256);
  k_affine<<<1, 128, 0, stream>>>(stats + 256, g2, be2, affine + 256, affine + 384);
  // layer 3
  k_gemm<<<ngemm, 256, 0, stream>>>(bufB, W3, affine + 256, affine + 384, dinv, Abf);
  k_agg<<<nagg, 256, 0, stream>>>(Abf, off, csr, dinv, b3, bufB, stats + 512);
  k_affine<<<1, 128, 0, stream>>>(stats + 512, g3, be3, affine + 512, affine + 640);
  // pool + fc
  k_pool<<<NG, 128, 0, stream>>>(bufB, affine + 512, affine + 640, gstart, fcW, fcb, out);
}

// Round 9
// 533.498 us; speedup vs baseline: 1.0636x; 1.0636x over previous
//
#include <hip/hip_runtime.h>

#define NN 50000
#define NE 600000
#define NG 512
#define HD 128
#define EPSV 1e-5f

typedef unsigned int uint;

__device__ inline void atomicAddF(float* p, float v) {
  __hip_atomic_fetch_add(p, v, __ATOMIC_RELAXED, __HIP_MEMORY_SCOPE_AGENT);
}

__device__ inline uint bf16rne(float f) {
  uint u = __float_as_uint(f);
  return (u + 0x7fffu + ((u >> 16) & 1u)) >> 16;
}
__device__ inline uint pack2bf(float a, float b) {
  return bf16rne(a) | (bf16rne(b) << 16);
}
__device__ inline float lo16f(uint u) { return __uint_as_float(u << 16); }
__device__ inline float hi16f(uint u) { return __uint_as_float(u & 0xffff0000u); }

// ---- CSR build (self-edge first in each node's list) ----
__global__ __launch_bounds__(256) void k_count(const int* __restrict__ dst, int* __restrict__ cnt) {
  int e = blockIdx.x * 256 + threadIdx.x;
  if (e < NE) atomicAdd(&cnt[dst[e]], 1);
}

// 4 elements per thread, 13 iterations; also zeroes Abf's pad row NN.
__global__ __launch_bounds__(1024) void k_scan(const int* __restrict__ cnt, int* __restrict__ off,
                                               int* __restrict__ cursor, float* __restrict__ dinv,
                                               int* __restrict__ csr, uint* __restrict__ zrow) {
  __shared__ int part[16];
  __shared__ int partscan[16];
  int t = threadIdx.x;
  int lane = t & 63, w = t >> 6;
  if (t < 64) zrow[t] = 0u;   // zero pad row (bf16 row = 64 uints)
  int carry = 0;
  for (int base = 0; base < NN; base += 4096) {
    int i0 = base + 4 * t;
    int c[4], v[4];
#pragma unroll
    for (int j = 0; j < 4; j++) {
      int idx = i0 + j;
      c[j] = (idx < NN) ? cnt[idx] : 0;
      v[j] = (idx < NN) ? (c[j] + 1) : 0;
    }
    int tsum = (v[0] + v[1]) + (v[2] + v[3]);
    int val = tsum;
#pragma unroll
    for (int s = 1; s < 64; s <<= 1) {
      int u = __shfl_up(val, s);
      if (lane >= s) val += u;
    }
    if (lane == 63) part[w] = val;
    __syncthreads();
    if (t == 0) {
      int acc = 0;
#pragma unroll
      for (int i = 0; i < 16; i++) { acc += part[i]; partscan[i] = acc; }
    }
    __syncthreads();
    int waveoff = (w > 0) ? partscan[w - 1] : 0;
    int run = val - tsum + waveoff + carry;
#pragma unroll
    for (int j = 0; j < 4; j++) {
      int idx = i0 + j;
      if (idx < NN) {
        off[idx] = run;
        cursor[idx] = run + 1;
        csr[run] = idx;                        // self-edge
        dinv[idx] = rsqrtf((float)c[j] + 1.0f);
        run += v[j];
      }
    }
    carry += partscan[15];
    __syncthreads();
  }
  if (t == 0) off[NN] = carry;
}

__global__ __launch_bounds__(256) void k_fill(const int* __restrict__ src, const int* __restrict__ dst,
                                              int* __restrict__ cursor, int* __restrict__ csr) {
  int e = blockIdx.x * 256 + threadIdx.x;
  if (e < NE) {
    int p = atomicAdd(&cursor[dst[e]], 1);
    csr[p] = src[e];
  }
}

// ---- fused embedding tables: T = emb @ W1[rows] ----
__global__ __launch_bounds__(128) void k_tabs(const float* __restrict__ emb0, const float* __restrict__ emb1,
                                              const float* __restrict__ emb2, const float* __restrict__ emb5,
                                              const float* __restrict__ W1, float* __restrict__ tabs,
                                              float* __restrict__ row0) {
  int r = blockIdx.x, f = threadIdx.x;
  if (r == 470) { row0[f] = W1[f]; return; }
  const float* e;
  int wbase;
  if (r < 96)      { e = emb0 + r * 32;        wbase = 1;  }
  else if (r < 192){ e = emb1 + (r - 96) * 32; wbase = 33; }
  else if (r < 288){ e = emb2 + (r - 192) * 32; wbase = 65; }
  else             { e = emb5 + (r - 288) * 32; wbase = 97; }
  float acc = 0.f;
#pragma unroll 8
  for (int k = 0; k < 32; k++) acc += e[k] * W1[(wbase + k) * HD + f];
  tabs[r * HD + f] = acc;
}

// ---- layer-1: embed + axpy + pre-scale by dinv; packed bf16 output ----
__global__ __launch_bounds__(256) void k_embed(const float* __restrict__ x, const float2* __restrict__ tabs2,
                                               const float2* __restrict__ row02, const float* __restrict__ dinv,
                                               uint* __restrict__ Abf) {
  int n = blockIdx.x * 4 + (threadIdx.x >> 6);   // grid exact: 12500*4 = NN
  int lane = threadIdx.x & 63;
  float poss = x[n * 5 + 0];
  int i0 = (int)x[n * 5 + 1];
  int i1 = (int)x[n * 5 + 2];
  int i2 = (int)x[n * 5 + 3];
  int i5 = (int)x[n * 5 + 4];
  float2 r0 = row02[lane];
  float2 t0 = tabs2[(size_t)i0 * 64 + lane];
  float2 t1 = tabs2[(size_t)(96 + i1) * 64 + lane];
  float2 t2 = tabs2[(size_t)(192 + i2) * 64 + lane];
  float2 t5 = tabs2[(size_t)(288 + i5) * 64 + lane];
  float hx = poss * r0.x + t0.x + t1.x + t2.x + t5.x;
  float hy = poss * r0.y + t0.y + t1.y + t2.y + t5.y;
  float dv = dinv[n];
  Abf[(size_t)n * 64 + lane] = pack2bf(hx * dv, hy * dv);
}

// ---- aggregation v9: v8 structure but Phase 2 FULLY UNROLLED so the
// 16-load clause lives in registers (v8 spilled to scratch via dynamic
// indexing under "#pragma unroll 1" -- rule #20).
#define AGG_NPW 4
#define AGG_NPB (4 * AGG_NPW)
__global__ __launch_bounds__(256) void k_agg(const uint* __restrict__ Abf, const int* __restrict__ off,
                                             const int* __restrict__ csr, const float* __restrict__ dinv,
                                             const float* __restrict__ bias, float* __restrict__ B,
                                             float* __restrict__ stats) {
  const int t = threadIdx.x, lane = t & 63, wave = t >> 6;
  const int grp = lane >> 4, p = lane & 15;
  __shared__ float sredb[16][17];   // [p][8 sums + 8 sumsqs], padded
  for (int q = t; q < 16 * 17; q += 256) ((float*)sredb)[q] = 0.f;
  __syncthreads();

  const float4 bias03 = ((const float4*)bias)[p * 2];
  const float4 bias47 = ((const float4*)bias)[p * 2 + 1];

  const int n0 = blockIdx.x * AGG_NPB + wave * AGG_NPW;   // grid exact
  int sv = 0;
  { int q = n0 + lane; if (lane <= AGG_NPW) sv = off[q]; }

  // preload all 4 nodes' first-64 edge indices
  int ev[AGG_NPW];
#pragma unroll
  for (int i = 0; i < AGG_NPW; i++) {
    int ks = __shfl(sv, i), ke = __shfl(sv, i + 1);
    int rem = ke - ks;
    ev[i] = (lane < rem) ? csr[ks + lane] : NN;
  }

  // ---- Phase 1: issue ALL first-batch gathers (16 loads, static names)
  uint4 v[AGG_NPW][4];
#pragma unroll
  for (int i = 0; i < AGG_NPW; i++) {
#pragma unroll
    for (int m = 0; m < 4; m++) {
      int nb = __shfl(ev[i], 4 * m + grp);   // pad slots give NN
      v[i][m] = *(const uint4*)((const char*)Abf + (((size_t)nb) << 8) + (p << 4));
    }
  }

  // ---- Phase 2: per-node consume (FULLY UNROLLED -> static v[i][m]) ----
#pragma unroll
  for (int i = 0; i < AGG_NPW; i++) {
    const int ks = __shfl(sv, i);
    const int ke = __shfl(sv, i + 1);
    const int deg = ke - ks;
    float acc[8] = {0.f, 0.f, 0.f, 0.f, 0.f, 0.f, 0.f, 0.f};
#pragma unroll
    for (int m = 0; m < 4; m++) {
      acc[0] += lo16f(v[i][m].x); acc[1] += hi16f(v[i][m].x);
      acc[2] += lo16f(v[i][m].y); acc[3] += hi16f(v[i][m].y);
      acc[4] += lo16f(v[i][m].z); acc[5] += hi16f(v[i][m].z);
      acc[6] += lo16f(v[i][m].w); acc[7] += hi16f(v[i][m].w);
    }
    // tail: edges 16..deg (15% of nodes; >64 ultra-rare)
#pragma unroll 1
    for (int c0 = 16; c0 < deg; c0 += 16) {
      uint4 w[4];
      if (c0 + 16 <= 64) {
#pragma unroll
        for (int m = 0; m < 4; m++) {
          int nb = __shfl(ev[i], c0 + 4 * m + grp);
          w[m] = *(const uint4*)((const char*)Abf + (((size_t)nb) << 8) + (p << 4));
        }
      } else {
        int rem2 = deg - c0;
        int evr = (lane < rem2) ? csr[ks + c0 + lane] : NN;
#pragma unroll
        for (int m = 0; m < 4; m++) {
          int nb = __shfl(evr, 4 * m + grp);
          w[m] = *(const uint4*)((const char*)Abf + (((size_t)nb) << 8) + (p << 4));
        }
      }
#pragma unroll
      for (int m = 0; m < 4; m++) {
        acc[0] += lo16f(w[m].x); acc[1] += hi16f(w[m].x);
        acc[2] += lo16f(w[m].y); acc[3] += hi16f(w[m].y);
        acc[4] += lo16f(w[m].z); acc[5] += hi16f(w[m].z);
        acc[6] += lo16f(w[m].w); acc[7] += hi16f(w[m].w);
      }
    }
    // combine the 4 lane-groups (disjoint neighbor subsets)
#pragma unroll
    for (int q = 0; q < 8; q++) {
      acc[q] += __shfl_xor(acc[q], 16);
      acc[q] += __shfl_xor(acc[q], 32);
    }
    const float dv = dinv[n0 + i];
    float o[8];
    o[0] = fmaf(acc[0], dv, bias03.x); o[1] = fmaf(acc[1], dv, bias03.y);
    o[2] = fmaf(acc[2], dv, bias03.z); o[3] = fmaf(acc[3], dv, bias03.w);
    o[4] = fmaf(acc[4], dv, bias47.x); o[5] = fmaf(acc[5], dv, bias47.y);
    o[6] = fmaf(acc[6], dv, bias47.z); o[7] = fmaf(acc[7], dv, bias47.w);
    if (grp == 0) {
      float4 w0 = make_float4(o[0], o[1], o[2], o[3]);
      float4 w1 = make_float4(o[4], o[5], o[6], o[7]);
      *(float4*)&B[(size_t)(n0 + i) * HD + p * 8] = w0;
      *(float4*)&B[(size_t)(n0 + i) * HD + p * 8 + 4] = w1;
#pragma unroll
      for (int q = 0; q < 8; q++) {
        atomicAdd(&sredb[p][q], o[q]);
        atomicAdd(&sredb[p][8 + q], o[q] * o[q]);
      }
    }
  }
  __syncthreads();
  {
    int pp = t >> 4, ii = t & 15;
    float v2 = sredb[pp][ii];
    atomicAddF(&stats[(ii < 8 ? 0 : 128) + pp * 8 + (ii & 7)], v2);
  }
}

// ---- BN finalize -> affine a,c ----
__global__ __launch_bounds__(128) void k_affine(const float* __restrict__ stats, const float* __restrict__ g,
                                                const float* __restrict__ be, float* __restrict__ af,
                                                float* __restrict__ cf) {
  int f = threadIdx.x;
  float mean = stats[f] * (1.f / NN);
  float var = stats[128 + f] * (1.f / NN) - mean * mean;
  var = fmaxf(var, 0.f);
  float inv = rsqrtf(var + EPSV);
  float a = g[f] * inv;
  af[f] = a;
  cf[f] = be[f] - mean * a;
}

// ---- GEMM: Abf[n,:] = bf16( dinv[n] * (relu(af*Bin[n,:]+cf) @ W) ) ----
#define GT_N 128
#define GT_KC 32
__global__ __launch_bounds__(256) void k_gemm(const float* __restrict__ Bin, const float* __restrict__ W,
                                              const float* __restrict__ af, const float* __restrict__ cf,
                                              const float* __restrict__ dinv, uint* __restrict__ Abf) {
  __shared__ float hs[GT_KC * 132];
  __shared__ float ws[GT_KC * 132];
  const int t = threadIdx.x;
  const int base = blockIdx.x * GT_N;
  const int tx = t & 15, ty = t >> 4;
  float acc[8][8];
#pragma unroll
  for (int a = 0; a < 8; a++)
#pragma unroll
    for (int b = 0; b < 8; b++) acc[a][b] = 0.f;

  for (int k0 = 0; k0 < HD; k0 += GT_KC) {
    __syncthreads();
    {
      const float4* W4 = (const float4*)(W + k0 * HD);
#pragma unroll
      for (int i = t; i < 1024; i += 256) {
        int row = i >> 5, c4 = i & 31;
        float4 v = W4[i];
        *(float4*)&ws[row * 132 + c4 * 4] = v;
      }
    }
    {
#pragma unroll
      for (int i = t; i < 1024; i += 256) {
        int node = i >> 3, c4 = i & 7;
        int n = base + node;
        float4 v = make_float4(0.f, 0.f, 0.f, 0.f);
        if (n < NN) v = *(const float4*)&Bin[(size_t)n * HD + k0 + c4 * 4];
        int kk = c4 * 4;
        float r0 = fmaxf(fmaf(af[k0 + kk + 0], v.x, cf[k0 + kk + 0]), 0.f);
        float r1 = fmaxf(fmaf(af[k0 + kk + 1], v.y, cf[k0 + kk + 1]), 0.f);
        float r2 = fmaxf(fmaf(af[k0 + kk + 2], v.z, cf[k0 + kk + 2]), 0.f);
        float r3 = fmaxf(fmaf(af[k0 + kk + 3], v.w, cf[k0 + kk + 3]), 0.f);
        hs[(kk + 0) * 132 + node] = r0;
        hs[(kk + 1) * 132 + node] = r1;
        hs[(kk + 2) * 132 + node] = r2;
        hs[(kk + 3) * 132 + node] = r3;
      }
    }
    __syncthreads();
#pragma unroll
    for (int k = 0; k < GT_KC; k++) {
      float4 h0 = *(float4*)&hs[k * 132 + ty * 8];
      float4 h1 = *(float4*)&hs[k * 132 + ty * 8 + 4];
      float4 w0 = *(float4*)&ws[k * 132 + tx * 8];
      float4 w1 = *(float4*)&ws[k * 132 + tx * 8 + 4];
      float hh[8] = {h0.x, h0.y, h0.z, h0.w, h1.x, h1.y, h1.z, h1.w};
      float wv[8] = {w0.x, w0.y, w0.z, w0.w, w1.x, w1.y, w1.z, w1.w};
#pragma unroll
      for (int a = 0; a < 8; a++)
#pragma unroll
        for (int b = 0; b < 8; b++) acc[a][b] = fmaf(hh[a], wv[b], acc[a][b]);
    }
  }
#pragma unroll
  for (int a = 0; a < 8; a++) {
    int n = base + ty * 8 + a;
    if (n < NN) {
      float s = dinv[n];
      uint4 o;
      o.x = pack2bf(acc[a][0] * s, acc[a][1] * s);
      o.y = pack2bf(acc[a][2] * s, acc[a][3] * s);
      o.z = pack2bf(acc[a][4] * s, acc[a][5] * s);
      o.w = pack2bf(acc[a][6] * s, acc[a][7] * s);
      *(uint4*)&Abf[(size_t)n * 64 + tx * 4] = o;
    }
  }
}

// ---- graph boundaries via binary search on sorted batch ----
__global__ __launch_bounds__(128) void k_bsearch(const int* __restrict__ batch, int* __restrict__ gstart) {
  int g = blockIdx.x * 128 + threadIdx.x;
  if (g > NG) return;
  if (g == NG) { gstart[NG] = NN; return; }
  int lo = 0, hi = NN;
  while (lo < hi) {
    int mid = (lo + hi) >> 1;
    if (batch[mid] < g) lo = mid + 1;
    else hi = mid;
  }
  gstart[g] = lo;
}

// ---- pool + FC ----
__global__ __launch_bounds__(128) void k_pool(const float* __restrict__ B, const float* __restrict__ af,
                                              const float* __restrict__ cf, const int* __restrict__ gstart,
                                              const float* __restrict__ fcW, const float* __restrict__ fcb,
                                              float* __restrict__ out) {
  int g = blockIdx.x, f = threadIdx.x;
  int gs = gstart[g], ge = gstart[g + 1];
  float a = af[f], c = cf[f];
  float a0 = 0.f, a1 = 0.f, a2 = 0.f, a3 = 0.f;
  int n = gs;
  for (; n + 4 <= ge; n += 4) {
    a0 += fmaxf(fmaf(a, B[(size_t)(n + 0) * HD + f], c), 0.f);
    a1 += fmaxf(fmaf(a, B[(size_t)(n + 1) * HD + f], c), 0.f);
    a2 += fmaxf(fmaf(a, B[(size_t)(n + 2) * HD + f], c), 0.f);
    a3 += fmaxf(fmaf(a, B[(size_t)(n + 3) * HD + f], c), 0.f);
  }
  for (; n < ge; n++) a0 += fmaxf(fmaf(a, B[(size_t)n * HD + f], c), 0.f);
  float acc = (a0 + a1) + (a2 + a3);
  float cntf = (float)(ge - gs);
  float pooled = acc / fmaxf(cntf, 1.f);
  __shared__ float lp[128];
  lp[f] = pooled;
  __syncthreads();
  if (f < 3) {
    float o = fcb[f];
    for (int k = 0; k < 128; k++) o += lp[k] * fcW[k * 3 + f];
    out[g * 3 + f] = o;
  }
}

extern "C" void kernel_launch(void* const* d_in, const int* in_sizes, int n_in,
                              void* d_out, int out_size, void* d_ws, size_t ws_size,
                              hipStream_t stream) {
  const float* x    = (const float*)d_in[0];
  const int* ei     = (const int*)d_in[1];
  const int* batch  = (const int*)d_in[2];
  const float* emb0 = (const float*)d_in[3];
  const float* emb1 = (const float*)d_in[4];
  const float* emb2 = (const float*)d_in[5];
  const float* emb5 = (const float*)d_in[6];
  const float* W1   = (const float*)d_in[7];
  const float* b1   = (const float*)d_in[8];
  const float* W2   = (const float*)d_in[9];
  const float* b2   = (const float*)d_in[10];
  const float* W3   = (const float*)d_in[11];
  const float* b3   = (const float*)d_in[12];
  const float* g1   = (const float*)d_in[13];
  const float* be1  = (const float*)d_in[14];
  const float* g2   = (const float*)d_in[15];
  const float* be2  = (const float*)d_in[16];
  const float* g3   = (const float*)d_in[17];
  const float* be3  = (const float*)d_in[18];
  const float* fcW  = (const float*)d_in[19];
  const float* fcb  = (const float*)d_in[20];
  float* out = (float*)d_out;

  const int* esrc = ei;
  const int* edst = ei + NE;

  char* p = (char*)d_ws;
  size_t o = 0;
  auto alloc = [&](size_t bytes) -> void* {
    o = (o + 255) & ~(size_t)255;
    void* r = p + o;
    o += bytes;
    return r;
  };
  int* cnt      = (int*)alloc(NN * 4);
  float* stats  = (float*)alloc(3 * 256 * 4);   // 3 layers x (sum,sumsq)
  size_t zbytes = o;                            // memset range covers cnt+stats
  int* off      = (int*)alloc((NN + 1) * 4);
  int* cursor   = (int*)alloc(NN * 4);
  int* csr      = (int*)alloc((size_t)(NE + NN + 64) * 4);
  float* dinv   = (float*)alloc(NN * 4);
  float* tabs   = (float*)alloc(470 * HD * 4);
  float* row0   = (float*)alloc(HD * 4);
  float* affine = (float*)alloc(3 * 256 * 4);   // 3 layers x (a,c)
  int* gstart   = (int*)alloc((NG + 1) * 4);
  uint* Abf     = (uint*)alloc((size_t)(NN + 1) * 64 * 4);   // bf16 rows, 256B each (+pad row)
  float* bufB   = (float*)alloc((size_t)NN * HD * 4);
  (void)ws_size; (void)n_in; (void)in_sizes; (void)out_size;

  hipMemsetAsync(d_ws, 0, zbytes, stream);

  k_count<<<(NE + 255) / 256, 256, 0, stream>>>(edst, cnt);
  k_scan<<<1, 1024, 0, stream>>>(cnt, off, cursor, dinv, csr, Abf + (size_t)NN * 64);
  k_fill<<<(NE + 255) / 256, 256, 0, stream>>>(esrc, edst, cursor, csr);
  k_tabs<<<471, 128, 0, stream>>>(emb0, emb1, emb2, emb5, W1, tabs, row0);
  k_bsearch<<<5, 128, 0, stream>>>(batch, gstart);
  k_embed<<<NN / 4, 256, 0, stream>>>(x, (const float2*)tabs, (const float2*)row0, dinv, Abf);

  const int nagg = NN / AGG_NPB;            // 3125, exact
  const int ngemm = (NN + GT_N - 1) / GT_N;

  // layer 1
  k_agg<<<nagg, 256, 0, stream>>>(Abf, off, csr, dinv, b1, bufB, stats + 0);
  k_affine<<<1, 128, 0, stream>>>(stats + 0, g1, be1, affine + 0, affine + 128);
  // layer 2
  k_gemm<<<ngemm, 256, 0, stream>>>(bufB, W2, affine + 0, affine + 128, dinv, Abf);
  k_agg<<<nagg, 256, 0, stream>>>(Abf, off, csr, dinv, b2, bufB, stats + 256);
  k_affine<<<1, 128, 0, stream>>>(stats + 256, g2, be2, affine + 256, affine + 384);
  // layer 3
  k_gemm<<<ngemm, 256, 0, stream>>>(bufB, W3, affine + 256, affine + 384, dinv, Abf);
  k_agg<<<nagg, 256, 0, stream>>>(Abf, off, csr, dinv, b3, bufB, stats + 512);
  k_affine<<<1, 128, 0, stream>>>(stats + 512, g3, be3, affine + 512, affine + 640);
  // pool + fc
  k_pool<<<NG, 128, 0, stream>>>(bufB, affine + 512, affine + 640, gstart, fcW, fcb, out);
}

// Round 10
// 451.413 us; speedup vs baseline: 1.2570x; 1.1818x over previous
//
#include <hip/hip_runtime.h>

#define NN 50000
#define NE 600000
#define NG 512
#define HD 128
#define EPSV 1e-5f
#define NSC 64            // stats scatter copies

typedef unsigned int uint;

__device__ inline void atomicAddF(float* p, float v) {
  __hip_atomic_fetch_add(p, v, __ATOMIC_RELAXED, __HIP_MEMORY_SCOPE_AGENT);
}

__device__ inline uint bf16rne(float f) {
  uint u = __float_as_uint(f);
  return (u + 0x7fffu + ((u >> 16) & 1u)) >> 16;
}
__device__ inline uint pack2bf(float a, float b) {
  return bf16rne(a) | (bf16rne(b) << 16);
}
__device__ inline float lo16f(uint u) { return __uint_as_float(u << 16); }
__device__ inline float hi16f(uint u) { return __uint_as_float(u & 0xffff0000u); }

// ---- prologue 1: count (blocks 0..2343) + tabs (2344..2814) + bsearch (2815..2817)
__global__ __launch_bounds__(256) void k_pro1(const int* __restrict__ dst, int* __restrict__ cnt,
                                              const float* __restrict__ emb0, const float* __restrict__ emb1,
                                              const float* __restrict__ emb2, const float* __restrict__ emb5,
                                              const float* __restrict__ W1, float* __restrict__ tabs,
                                              float* __restrict__ row0, const int* __restrict__ batch,
                                              int* __restrict__ gstart) {
  const int bid = blockIdx.x, t = threadIdx.x;
  if (bid < 2344) {
    int e = bid * 256 + t;
    if (e < NE) atomicAdd(&cnt[dst[e]], 1);
    return;
  }
  if (bid < 2815) {
    if (t >= 128) return;
    int r = bid - 2344, f = t;
    if (r == 470) { row0[f] = W1[f]; return; }
    const float* e;
    int wbase;
    if (r < 96)      { e = emb0 + r * 32;         wbase = 1;  }
    else if (r < 192){ e = emb1 + (r - 96) * 32;  wbase = 33; }
    else if (r < 288){ e = emb2 + (r - 192) * 32; wbase = 65; }
    else             { e = emb5 + (r - 288) * 32; wbase = 97; }
    float acc = 0.f;
#pragma unroll 8
    for (int k = 0; k < 32; k++) acc += e[k] * W1[(wbase + k) * HD + f];
    tabs[r * HD + f] = acc;
    return;
  }
  {
    int g = (bid - 2815) * 256 + t;
    if (g > NG) return;
    if (g == NG) { gstart[NG] = NN; return; }
    int lo = 0, hi = NN;
    while (lo < hi) {
      int mid = (lo + hi) >> 1;
      if (batch[mid] < g) lo = mid + 1;
      else hi = mid;
    }
    gstart[g] = lo;
  }
}

// ---- 3-phase scan over deg+1 (tile = 4096 elems/block, 13 blocks) ----
__global__ __launch_bounds__(1024) void k_scanA(const int* __restrict__ cnt, int* __restrict__ partials) {
  int t = threadIdx.x;
  int i0 = blockIdx.x * 4096 + 4 * t;
  int s = 0;
#pragma unroll
  for (int j = 0; j < 4; j++) {
    int idx = i0 + j;
    s += (idx < NN) ? (cnt[idx] + 1) : 0;
  }
#pragma unroll
  for (int d = 1; d < 64; d <<= 1) s += __shfl_xor(s, d);
  __shared__ int wsum[16];
  if ((t & 63) == 0) wsum[t >> 6] = s;
  __syncthreads();
  if (t == 0) {
    int tot = 0;
#pragma unroll
    for (int i = 0; i < 16; i++) tot += wsum[i];
    partials[blockIdx.x] = tot;
  }
}

__global__ __launch_bounds__(64) void k_scanB(int* __restrict__ partials, int* __restrict__ off) {
  if (threadIdx.x == 0) {
    int acc = 0;
#pragma unroll
    for (int i = 0; i < 13; i++) { int v = partials[i]; partials[i] = acc; acc += v; }
    partials[13] = acc;
    off[NN] = acc;
  }
}

__global__ __launch_bounds__(1024) void k_scanC(const int* __restrict__ cnt, const int* __restrict__ partials,
                                                int* __restrict__ off, int* __restrict__ cursor,
                                                float* __restrict__ dinv, int* __restrict__ csr,
                                                uint* __restrict__ zrow) {
  __shared__ int part[16];
  __shared__ int partscan[16];
  int t = threadIdx.x;
  int lane = t & 63, w = t >> 6;
  if (blockIdx.x == 0 && t < 64) zrow[t] = 0u;
  int i0 = blockIdx.x * 4096 + 4 * t;
  int c[4], v[4];
#pragma unroll
  for (int j = 0; j < 4; j++) {
    int idx = i0 + j;
    c[j] = (idx < NN) ? cnt[idx] : 0;
    v[j] = (idx < NN) ? (c[j] + 1) : 0;
  }
  int tsum = (v[0] + v[1]) + (v[2] + v[3]);
  int val = tsum;
#pragma unroll
  for (int s = 1; s < 64; s <<= 1) {
    int u = __shfl_up(val, s);
    if (lane >= s) val += u;
  }
  if (lane == 63) part[w] = val;
  __syncthreads();
  if (t == 0) {
    int acc = 0;
#pragma unroll
    for (int i = 0; i < 16; i++) { acc += part[i]; partscan[i] = acc; }
  }
  __syncthreads();
  int waveoff = (w > 0) ? partscan[w - 1] : 0;
  int run = val - tsum + waveoff + partials[blockIdx.x];
#pragma unroll
  for (int j = 0; j < 4; j++) {
    int idx = i0 + j;
    if (idx < NN) {
      off[idx] = run;
      cursor[idx] = run + 1;
      csr[run] = idx;                        // self-edge
      dinv[idx] = rsqrtf((float)c[j] + 1.0f);
      run += v[j];
    }
  }
}

// ---- prologue 2: fill (blocks 0..2343) + embed (2344..14843) ----
__global__ __launch_bounds__(256) void k_pro2(const int* __restrict__ src, const int* __restrict__ dst,
                                              int* __restrict__ cursor, int* __restrict__ csr,
                                              const float* __restrict__ x, const float2* __restrict__ tabs2,
                                              const float2* __restrict__ row02, const float* __restrict__ dinv,
                                              uint* __restrict__ Abf) {
  const int bid = blockIdx.x, t = threadIdx.x;
  if (bid < 2344) {
    int e = bid * 256 + t;
    if (e < NE) {
      int p = atomicAdd(&cursor[dst[e]], 1);
      csr[p] = src[e];
    }
    return;
  }
  int n = (bid - 2344) * 4 + (t >> 6);   // exact: 12500*4 = NN
  int lane = t & 63;
  float poss = x[n * 5 + 0];
  int i0 = (int)x[n * 5 + 1];
  int i1 = (int)x[n * 5 + 2];
  int i2 = (int)x[n * 5 + 3];
  int i5 = (int)x[n * 5 + 4];
  float2 r0 = row02[lane];
  float2 t0 = tabs2[(size_t)i0 * 64 + lane];
  float2 t1 = tabs2[(size_t)(96 + i1) * 64 + lane];
  float2 t2 = tabs2[(size_t)(192 + i2) * 64 + lane];
  float2 t5 = tabs2[(size_t)(288 + i5) * 64 + lane];
  float hx = poss * r0.x + t0.x + t1.x + t2.x + t5.x;
  float hy = poss * r0.y + t0.y + t1.y + t2.y + t5.y;
  float dv = dinv[n];
  Abf[(size_t)n * 64 + lane] = pack2bf(hx * dv, hy * dv);
}

// ---- aggregation v10: v9 gather structure; stats atomics scattered across
// NSC=64 copies (stats[64][256]) to kill same-line atomic serialization.
#define AGG_NPW 4
#define AGG_NPB (4 * AGG_NPW)
__global__ __launch_bounds__(256) void k_agg(const uint* __restrict__ Abf, const int* __restrict__ off,
                                             const int* __restrict__ csr, const float* __restrict__ dinv,
                                             const float* __restrict__ bias, float* __restrict__ B,
                                             float* __restrict__ stats) {
  const int t = threadIdx.x, lane = t & 63, wave = t >> 6;
  const int grp = lane >> 4, p = lane & 15;
  __shared__ float sredb[16][17];   // [p][8 sums + 8 sumsqs], padded
  for (int q = t; q < 16 * 17; q += 256) ((float*)sredb)[q] = 0.f;
  __syncthreads();

  const float4 bias03 = ((const float4*)bias)[p * 2];
  const float4 bias47 = ((const float4*)bias)[p * 2 + 1];

  const int n0 = blockIdx.x * AGG_NPB + wave * AGG_NPW;   // grid exact
  int sv = 0;
  { int q = n0 + lane; if (lane <= AGG_NPW) sv = off[q]; }

  // preload all 4 nodes' first-64 edge indices
  int ev[AGG_NPW];
#pragma unroll
  for (int i = 0; i < AGG_NPW; i++) {
    int ks = __shfl(sv, i), ke = __shfl(sv, i + 1);
    int rem = ke - ks;
    ev[i] = (lane < rem) ? csr[ks + lane] : NN;
  }

  // ---- Phase 1: issue ALL first-batch gathers (16 loads, static names)
  uint4 v[AGG_NPW][4];
#pragma unroll
  for (int i = 0; i < AGG_NPW; i++) {
#pragma unroll
    for (int m = 0; m < 4; m++) {
      int nb = __shfl(ev[i], 4 * m + grp);   // pad slots give NN
      v[i][m] = *(const uint4*)((const char*)Abf + (((size_t)nb) << 8) + (p << 4));
    }
  }

  // ---- Phase 2: per-node consume (fully unrolled -> static v[i][m]) ----
#pragma unroll
  for (int i = 0; i < AGG_NPW; i++) {
    const int ks = __shfl(sv, i);
    const int ke = __shfl(sv, i + 1);
    const int deg = ke - ks;
    float acc[8] = {0.f, 0.f, 0.f, 0.f, 0.f, 0.f, 0.f, 0.f};
#pragma unroll
    for (int m = 0; m < 4; m++) {
      acc[0] += lo16f(v[i][m].x); acc[1] += hi16f(v[i][m].x);
      acc[2] += lo16f(v[i][m].y); acc[3] += hi16f(v[i][m].y);
      acc[4] += lo16f(v[i][m].z); acc[5] += hi16f(v[i][m].z);
      acc[6] += lo16f(v[i][m].w); acc[7] += hi16f(v[i][m].w);
    }
    // tail: edges 16..deg (15% of nodes; >64 ultra-rare)
#pragma unroll 1
    for (int c0 = 16; c0 < deg; c0 += 16) {
      uint4 w[4];
      if (c0 + 16 <= 64) {
#pragma unroll
        for (int m = 0; m < 4; m++) {
          int nb = __shfl(ev[i], c0 + 4 * m + grp);
          w[m] = *(const uint4*)((const char*)Abf + (((size_t)nb) << 8) + (p << 4));
        }
      } else {
        int rem2 = deg - c0;
        int evr = (lane < rem2) ? csr[ks + c0 + lane] : NN;
#pragma unroll
        for (int m = 0; m < 4; m++) {
          int nb = __shfl(evr, 4 * m + grp);
          w[m] = *(const uint4*)((const char*)Abf + (((size_t)nb) << 8) + (p << 4));
        }
      }
#pragma unroll
      for (int m = 0; m < 4; m++) {
        acc[0] += lo16f(w[m].x); acc[1] += hi16f(w[m].x);
        acc[2] += lo16f(w[m].y); acc[3] += hi16f(w[m].y);
        acc[4] += lo16f(w[m].z); acc[5] += hi16f(w[m].z);
        acc[6] += lo16f(w[m].w); acc[7] += hi16f(w[m].w);
      }
    }
    // combine the 4 lane-groups (disjoint neighbor subsets)
#pragma unroll
    for (int q = 0; q < 8; q++) {
      acc[q] += __shfl_xor(acc[q], 16);
      acc[q] += __shfl_xor(acc[q], 32);
    }
    const float dv = dinv[n0 + i];
    float o[8];
    o[0] = fmaf(acc[0], dv, bias03.x); o[1] = fmaf(acc[1], dv, bias03.y);
    o[2] = fmaf(acc[2], dv, bias03.z); o[3] = fmaf(acc[3], dv, bias03.w);
    o[4] = fmaf(acc[4], dv, bias47.x); o[5] = fmaf(acc[5], dv, bias47.y);
    o[6] = fmaf(acc[6], dv, bias47.z); o[7] = fmaf(acc[7], dv, bias47.w);
    if (grp == 0) {
      float4 w0 = make_float4(o[0], o[1], o[2], o[3]);
      float4 w1 = make_float4(o[4], o[5], o[6], o[7]);
      *(float4*)&B[(size_t)(n0 + i) * HD + p * 8] = w0;
      *(float4*)&B[(size_t)(n0 + i) * HD + p * 8 + 4] = w1;
#pragma unroll
      for (int q = 0; q < 8; q++) {
        atomicAdd(&sredb[p][q], o[q]);
        atomicAdd(&sredb[p][8 + q], o[q] * o[q]);
      }
    }
  }
  __syncthreads();
  {
    float* sp = stats + ((blockIdx.x & (NSC - 1)) << 8);   // 64-way scatter
    int pp = t >> 4, ii = t & 15;
    float v2 = sredb[pp][ii];
    atomicAddF(&sp[(ii < 8 ? 0 : 128) + pp * 8 + (ii & 7)], v2);
  }
}

// ---- BN finalize (sums NSC partial copies) -> affine a,c ----
__global__ __launch_bounds__(128) void k_affine(const float* __restrict__ stats, const float* __restrict__ g,
                                                const float* __restrict__ be, float* __restrict__ af,
                                                float* __restrict__ cf) {
  int f = threadIdx.x;
  float s1 = 0.f, s2 = 0.f;
#pragma unroll 4
  for (int i = 0; i < NSC; i++) {
    s1 += stats[i * 256 + f];
    s2 += stats[i * 256 + 128 + f];
  }
  float mean = s1 * (1.f / NN);
  float var = s2 * (1.f / NN) - mean * mean;
  var = fmaxf(var, 0.f);
  float inv = rsqrtf(var + EPSV);
  float a = g[f] * inv;
  af[f] = a;
  cf[f] = be[f] - mean * a;
}

// ---- GEMM: Abf[n,:] = bf16( dinv[n] * (relu(af*Bin[n,:]+cf) @ W) ) ----
#define GT_N 128
#define GT_KC 32
__global__ __launch_bounds__(256) void k_gemm(const float* __restrict__ Bin, const float* __restrict__ W,
                                              const float* __restrict__ af, const float* __restrict__ cf,
                                              const float* __restrict__ dinv, uint* __restrict__ Abf) {
  __shared__ float hs[GT_KC * 132];
  __shared__ float ws[GT_KC * 132];
  const int t = threadIdx.x;
  const int base = blockIdx.x * GT_N;
  const int tx = t & 15, ty = t >> 4;
  float acc[8][8];
#pragma unroll
  for (int a = 0; a < 8; a++)
#pragma unroll
    for (int b = 0; b < 8; b++) acc[a][b] = 0.f;

  for (int k0 = 0; k0 < HD; k0 += GT_KC) {
    __syncthreads();
    {
      const float4* W4 = (const float4*)(W + k0 * HD);
#pragma unroll
      for (int i = t; i < 1024; i += 256) {
        int row = i >> 5, c4 = i & 31;
        float4 v = W4[i];
        *(float4*)&ws[row * 132 + c4 * 4] = v;
      }
    }
    {
#pragma unroll
      for (int i = t; i < 1024; i += 256) {
        int node = i >> 3, c4 = i & 7;
        int n = base + node;
        float4 v = make_float4(0.f, 0.f, 0.f, 0.f);
        if (n < NN) v = *(const float4*)&Bin[(size_t)n * HD + k0 + c4 * 4];
        int kk = c4 * 4;
        float r0 = fmaxf(fmaf(af[k0 + kk + 0], v.x, cf[k0 + kk + 0]), 0.f);
        float r1 = fmaxf(fmaf(af[k0 + kk + 1], v.y, cf[k0 + kk + 1]), 0.f);
        float r2 = fmaxf(fmaf(af[k0 + kk + 2], v.z, cf[k0 + kk + 2]), 0.f);
        float r3 = fmaxf(fmaf(af[k0 + kk + 3], v.w, cf[k0 + kk + 3]), 0.f);
        hs[(kk + 0) * 132 + node] = r0;
        hs[(kk + 1) * 132 + node] = r1;
        hs[(kk + 2) * 132 + node] = r2;
        hs[(kk + 3) * 132 + node] = r3;
      }
    }
    __syncthreads();
#pragma unroll
    for (int k = 0; k < GT_KC; k++) {
      float4 h0 = *(float4*)&hs[k * 132 + ty * 8];
      float4 h1 = *(float4*)&hs[k * 132 + ty * 8 + 4];
      float4 w0 = *(float4*)&ws[k * 132 + tx * 8];
      float4 w1 = *(float4*)&ws[k * 132 + tx * 8 + 4];
      float hh[8] = {h0.x, h0.y, h0.z, h0.w, h1.x, h1.y, h1.z, h1.w};
      float wv[8] = {w0.x, w0.y, w0.z, w0.w, w1.x, w1.y, w1.z, w1.w};
#pragma unroll
      for (int a = 0; a < 8; a++)
#pragma unroll
        for (int b = 0; b < 8; b++) acc[a][b] = fmaf(hh[a], wv[b], acc[a][b]);
    }
  }
#pragma unroll
  for (int a = 0; a < 8; a++) {
    int n = base + ty * 8 + a;
    if (n < NN) {
      float s = dinv[n];
      uint4 o;
      o.x = pack2bf(acc[a][0] * s, acc[a][1] * s);
      o.y = pack2bf(acc[a][2] * s, acc[a][3] * s);
      o.z = pack2bf(acc[a][4] * s, acc[a][5] * s);
      o.w = pack2bf(acc[a][6] * s, acc[a][7] * s);
      *(uint4*)&Abf[(size_t)n * 64 + tx * 4] = o;
    }
  }
}

// ---- pool + FC (2 node-lanes x 128 features) ----
__global__ __launch_bounds__(256) void k_pool(const float* __restrict__ B, const float* __restrict__ af,
                                              const float* __restrict__ cf, const int* __restrict__ gstart,
                                              const float* __restrict__ fcW, const float* __restrict__ fcb,
                                              float* __restrict__ out) {
  int g = blockIdx.x, t = threadIdx.x;
  int r = t >> 7, f = t & 127;
  int gs = gstart[g], ge = gstart[g + 1];
  float a = af[f], c = cf[f];
  float a0 = 0.f, a1 = 0.f, a2 = 0.f, a3 = 0.f;
  int n = gs + r;
  for (; n + 6 < ge; n += 8) {
    a0 += fmaxf(fmaf(a, B[(size_t)(n + 0) * HD + f], c), 0.f);
    a1 += fmaxf(fmaf(a, B[(size_t)(n + 2) * HD + f], c), 0.f);
    a2 += fmaxf(fmaf(a, B[(size_t)(n + 4) * HD + f], c), 0.f);
    a3 += fmaxf(fmaf(a, B[(size_t)(n + 6) * HD + f], c), 0.f);
  }
  for (; n < ge; n += 2) a0 += fmaxf(fmaf(a, B[(size_t)n * HD + f], c), 0.f);
  float acc = (a0 + a1) + (a2 + a3);
  __shared__ float lp[256];
  lp[t] = acc;
  __syncthreads();
  if (r == 0) {
    float pooled = (lp[f] + lp[f + 128]) / fmaxf((float)(ge - gs), 1.f);
    lp[f] = pooled;
  }
  __syncthreads();
  if (t < 3) {
    float o = fcb[t];
    for (int k = 0; k < 128; k++) o += lp[k] * fcW[k * 3 + t];
    out[g * 3 + t] = o;
  }
}

extern "C" void kernel_launch(void* const* d_in, const int* in_sizes, int n_in,
                              void* d_out, int out_size, void* d_ws, size_t ws_size,
                              hipStream_t stream) {
  const float* x    = (const float*)d_in[0];
  const int* ei     = (const int*)d_in[1];
  const int* batch  = (const int*)d_in[2];
  const float* emb0 = (const float*)d_in[3];
  const float* emb1 = (const float*)d_in[4];
  const float* emb2 = (const float*)d_in[5];
  const float* emb5 = (const float*)d_in[6];
  const float* W1   = (const float*)d_in[7];
  const float* b1   = (const float*)d_in[8];
  const float* W2   = (const float*)d_in[9];
  const float* b2   = (const float*)d_in[10];
  const float* W3   = (const float*)d_in[11];
  const float* b3   = (const float*)d_in[12];
  const float* g1   = (const float*)d_in[13];
  const float* be1  = (const float*)d_in[14];
  const float* g2   = (const float*)d_in[15];
  const float* be2  = (const float*)d_in[16];
  const float* g3   = (const float*)d_in[17];
  const float* be3  = (const float*)d_in[18];
  const float* fcW  = (const float*)d_in[19];
  const float* fcb  = (const float*)d_in[20];
  float* out = (float*)d_out;

  const int* esrc = ei;
  const int* edst = ei + NE;

  char* p = (char*)d_ws;
  size_t o = 0;
  auto alloc = [&](size_t bytes) -> void* {
    o = (o + 255) & ~(size_t)255;
    void* r = p + o;
    o += bytes;
    return r;
  };
  int* cnt      = (int*)alloc(NN * 4);
  float* stats  = (float*)alloc(3 * NSC * 256 * 4);   // 3 layers x 64 copies x (sum,sumsq)
  size_t zbytes = o;                                  // memset covers cnt+stats
  int* off      = (int*)alloc((NN + 1) * 4);
  int* cursor   = (int*)alloc(NN * 4);
  int* csr      = (int*)alloc((size_t)(NE + NN + 64) * 4);
  float* dinv   = (float*)alloc(NN * 4);
  float* tabs   = (float*)alloc(470 * HD * 4);
  float* row0   = (float*)alloc(HD * 4);
  float* affine = (float*)alloc(3 * 256 * 4);         // 3 layers x (a,c)
  int* gstart   = (int*)alloc((NG + 1) * 4);
  int* partials = (int*)alloc(16 * 4);
  uint* Abf     = (uint*)alloc((size_t)(NN + 1) * 64 * 4);   // bf16 rows (+pad row)
  float* bufB   = (float*)alloc((size_t)NN * HD * 4);
  (void)ws_size; (void)n_in; (void)in_sizes; (void)out_size;

  hipMemsetAsync(d_ws, 0, zbytes, stream);

  k_pro1<<<2818, 256, 0, stream>>>(edst, cnt, emb0, emb1, emb2, emb5, W1, tabs, row0, batch, gstart);
  k_scanA<<<13, 1024, 0, stream>>>(cnt, partials);
  k_scanB<<<1, 64, 0, stream>>>(partials, off);
  k_scanC<<<13, 1024, 0, stream>>>(cnt, partials, off, cursor, dinv, csr, Abf + (size_t)NN * 64);
  k_pro2<<<14844, 256, 0, stream>>>(esrc, edst, cursor, csr, x, (const float2*)tabs,
                                    (const float2*)row0, dinv, Abf);

  const int nagg = NN / AGG_NPB;            // 3125, exact
  const int ngemm = (NN + GT_N - 1) / GT_N;
  float* st1 = stats;
  float* st2 = stats + NSC * 256;
  float* st3 = stats + 2 * NSC * 256;

  // layer 1
  k_agg<<<nagg, 256, 0, stream>>>(Abf, off, csr, dinv, b1, bufB, st1);
  k_affine<<<1, 128, 0, stream>>>(st1, g1, be1, affine + 0, affine + 128);
  // layer 2
  k_gemm<<<ngemm, 256, 0, stream>>>(bufB, W2, affine + 0, affine + 128, dinv, Abf);
  k_agg<<<nagg, 256, 0, stream>>>(Abf, off, csr, dinv, b2, bufB, st2);
  k_affine<<<1, 128, 0, stream>>>(st2, g2, be2, affine + 256, affine + 384);
  // layer 3
  k_gemm<<<ngemm, 256, 0, stream>>>(bufB, W3, affine + 256, affine + 384, dinv, Abf);
  k_agg<<<nagg, 256, 0, stream>>>(Abf, off, csr, dinv, b3, bufB, st3);
  k_affine<<<1, 128, 0, stream>>>(st3, g3, be3, affine + 512, affine + 640);
  // pool + fc
  k_pool<<<NG, 256, 0, stream>>>(bufB, affine + 512, affine + 640, gstart, fcW, fcb, out);
}